// Round 3
// baseline (249.313 us; speedup 1.0000x reference)
//
#include <hip/hip_runtime.h>
#include <stdint.h>

typedef __attribute__((ext_vector_type(8))) __bf16 bf16x8;
typedef __attribute__((ext_vector_type(4))) float f32x4;

// Selected upper-tri circular-adjacency pairs (r,c), row-major triu order. K=64.
__device__ const unsigned char dR[64] = {
  0,0,0,0,0,0,0,
  1,1,1,1,1,1,
  2,2,2,2,2,
  3,3,3,3,
  4,4,4,4,
  5,5,5,5,
  6,6,6,6,
  7,7,7,7,
  8,8,8,8,
  9,9,9,9,
  10,10,10,10,
  11,11,11,11,
  12,12,12,12,
  13,13,13,
  14,14,
  15};
__device__ const unsigned char dC[64] = {
  0,1,2,3,13,14,15,
  1,2,3,4,14,15,
  2,3,4,5,15,
  3,4,5,6,
  4,5,6,7,
  5,6,7,8,
  6,7,8,9,
  7,8,9,10,
  8,9,10,11,
  9,10,11,12,
  10,11,12,13,
  11,12,13,14,
  12,13,14,15,
  13,14,15,
  14,15,
  15};

__device__ __forceinline__ unsigned short f2bf(float x){
  unsigned u = __builtin_bit_cast(unsigned, x);
  return (unsigned short)((u + 0x7FFFu + ((u >> 16) & 1u)) >> 16);
}

// fp32 -> bf16 weight conversion into workspace (2.62 MB total)
__global__ void conv_w_kernel(const float* __restrict__ w1, const float* __restrict__ w2,
                              unsigned short* __restrict__ o1, unsigned short* __restrict__ o2){
  int i = blockIdx.x * 256 + threadIdx.x;
  if (i < 262144){                       // W1: 512*2048 = 262144 float4 groups
    float4 v = ((const float4*)w1)[i];
    ushort4 pk; pk.x=f2bf(v.x); pk.y=f2bf(v.y); pk.z=f2bf(v.z); pk.w=f2bf(v.w);
    ((ushort4*)o1)[i] = pk;
  } else {
    int j = i - 262144;
    if (j < 65536){                      // W2: 512*512
      float4 v = ((const float4*)w2)[j];
      ushort4 pk; pk.x=f2bf(v.x); pk.y=f2bf(v.y); pk.z=f2bf(v.z); pk.w=f2bf(v.w);
      ((ushort4*)o2)[j] = pk;
    }
  }
}

// Gather loads for next mega: g[fl][par][o] <- fp32 from global (issued EARLY in mega body)
#define GISSUE(mm, fl) do{ const int fo_ = ((mm)*4 + (fl)) << 16;                         \
  _Pragma("unroll") for (int par_ = 0; par_ < 4; ++par_)                                  \
  _Pragma("unroll") for (int o_ = 0; o_ < 3; ++o_)                                        \
    g[fl][par_][o_] = xb[fo_ + poff[par_][o_]]; }while(0)

// Convert + LDS write of chunk fl into buffer bb (placed LATE in mega body)
#define GWRITE(bb, fl) do{ char* wb_ = lds + (bb)*49152 + ((fl)<<12) + wbase;             \
  _Pragma("unroll") for (int par_ = 0; par_ < 4; ++par_)                                  \
  _Pragma("unroll") for (int o_ = 0; o_ < 3; ++o_)                                        \
    *(unsigned short*)(wb_ + o_*16384 + qoff[par_]) = f2bf(g[fl][par_][o_]); }while(0)

// One K=32 sub-step of phase 1: 4 W-frag loads (L2), 6 LDS A-frag reads, 24 MFMA
#define SUB(bb, mm, ss) do{                                                               \
  bf16x8 bw_[4];                                                                          \
  _Pragma("unroll") for (int ct_ = 0; ct_ < 4; ++ct_)                                     \
    bw_[ct_] = *(const bf16x8*)(bp1[ct_] + ((mm)<<9) + ((ss)<<6));                        \
  bf16x8 af_[2][3];                                                                       \
  _Pragma("unroll") for (int tf_ = 0; tf_ < 2; ++tf_)                                     \
  _Pragma("unroll") for (int o_ = 0; o_ < 3; ++o_)                                        \
    af_[tf_][o_] = *(const bf16x8*)(lds + (bb)*49152 + o_*16384 + ((ss)<<11) + (tf_<<10) + (q<<8) + (lr<<4)); \
  _Pragma("unroll") for (int ct_ = 0; ct_ < 4; ++ct_)                                     \
  _Pragma("unroll") for (int tf_ = 0; tf_ < 2; ++tf_)                                     \
  _Pragma("unroll") for (int o_ = 0; o_ < 3; ++o_)                                        \
    acc[o_][tf_][ct_] = __builtin_amdgcn_mfma_f32_16x16x32_bf16(af_[tf_][o_], bw_[ct_], acc[o_][tf_][ct_], 0, 0, 0); \
}while(0)

// One K=32 sub-step of phase 2: 6 swizzled A1 reads, 24 MFMA (W2 frags in cc[])
#define A2SUB(ss, cc) do{                                                                 \
  bf16x8 a2_[2][3];                                                                       \
  _Pragma("unroll") for (int tf_ = 0; tf_ < 2; ++tf_)                                     \
  _Pragma("unroll") for (int o_ = 0; o_ < 3; ++o_){                                       \
    const int trow_ = (tf_<<4) + lr;                                                      \
    int byt_ = (((o_<<5) + trow_)<<10) + ((ss)<<6) + (q<<4);                              \
    byt_ ^= (trow_ & 7) << 4;                                                             \
    a2_[tf_][o_] = *(const bf16x8*)(lds + byt_); }                                        \
  _Pragma("unroll") for (int ct_ = 0; ct_ < 4; ++ct_)                                     \
  _Pragma("unroll") for (int tf_ = 0; tf_ < 2; ++tf_)                                     \
  _Pragma("unroll") for (int o_ = 0; o_ < 3; ++o_)                                        \
    acc2[o_][tf_][ct_] = __builtin_amdgcn_mfma_f32_16x16x32_bf16(a2_[tf_][o_], cc[ct_], acc2[o_][tf_][ct_], 0, 0, 0); \
}while(0)

// Block = (b, 32-t tile). 256 blocks, 512 threads (8 waves), 96 KiB LDS -> 1 block/CU.
// LDS: phase 1: dbuf 2 x [3o][8sub][2tf][4q][16t][8e] bf16 = 2 x 49152
//      phase 2: A1 [3o*32t][512h] bf16 swizzled = 98304 (aliases dbuf after final barrier)
__global__ __launch_bounds__(512, 2)
void fused_kernel(const float* __restrict__ x,
                  const float* __restrict__ b1v,
                  const float* __restrict__ b2v,
                  const unsigned short* __restrict__ w1b,
                  const unsigned short* __restrict__ w2b,
                  float* __restrict__ out)
{
  __shared__ char lds[98304];
  const int bid = blockIdx.x;
  const int b   = bid >> 3;
  const int t0  = (bid & 7) << 5;

  const int tid  = threadIdx.x;
  const int w    = tid >> 6;
  const int lane = tid & 63;
  const int q    = lane >> 4;
  const int lr   = lane & 15;

  // gather role: thread = (klA in [0,16), tA in [0,32))
  const int klA = tid >> 5;
  const int tA  = tid & 31;
  const int tfA = tA >> 4, tl = tA & 15;

  int poff[4][3];
  int qoff[4];
#pragma unroll
  for (int par = 0; par < 4; ++par){
    const int k = par * 16 + klA;
    const int r = dR[k], c = dC[k];
#pragma unroll
    for (int o = 0; o < 3; ++o){
      const int v = o - 1;                       // mean over o is order-free
      poff[par][o] = ((((r - v) & 15) << 4) | ((c - v) & 15)) << 8;
    }
    qoff[par] = ((par >> 1) << 11) + ((((par << 1) + (klA >> 3)) & 3) << 8);
  }
  const int wbase = (tfA << 10) + (tl << 4) + ((klA & 7) << 1);
  const float* xb = x + (((long)b << 21) + t0 + tA);

  // phase-1 B pointers (direct L2 fragment loads of W1)
  const char* bp1[4];
  float b1c[4];
#pragma unroll
  for (int ct = 0; ct < 4; ++ct){
    const int col = (w << 6) + (ct << 4) + lr;
    bp1[ct] = (const char*)w1b + col * 4096 + (q << 4);
    b1c[ct] = b1v[col];
  }

  f32x4 acc[3][2][4];
#pragma unroll
  for (int o = 0; o < 3; ++o)
#pragma unroll
    for (int tf = 0; tf < 2; ++tf)
#pragma unroll
      for (int ct = 0; ct < 4; ++ct)
        acc[o][tf][ct] = f32x4{0.f, 0.f, 0.f, 0.f};

  float g[4][4][3];

  // ---------------- prologue: stage mega 0 into buf0 ----------------
  GISSUE(0, 0); GISSUE(0, 1); GISSUE(0, 2); GISSUE(0, 3);
  GWRITE(0, 0); GWRITE(0, 1); GWRITE(0, 2); GWRITE(0, 3);
  __syncthreads();

  // ---------------- phase 1: 8 megas of K=256, one barrier each ----------------
#pragma unroll 1
  for (int it = 0; it < 4; ++it){
    const int m0 = it << 1;
    // even mega m0 (buf0), stage m0+1 into buf1
    GISSUE(m0 + 1, 0); GISSUE(m0 + 1, 1);
    SUB(0, m0, 0); SUB(0, m0, 1);
    GWRITE(1, 0); GISSUE(m0 + 1, 2);
    SUB(0, m0, 2); SUB(0, m0, 3);
    GWRITE(1, 1); GISSUE(m0 + 1, 3);
    SUB(0, m0, 4); SUB(0, m0, 5);
    GWRITE(1, 2);
    SUB(0, m0, 6); SUB(0, m0, 7);
    GWRITE(1, 3);
    __syncthreads();
    // odd mega m0+1 (buf1), stage m0+2 into buf0 (skip on last)
    if (it < 3){ GISSUE(m0 + 2, 0); GISSUE(m0 + 2, 1); }
    SUB(1, m0 + 1, 0); SUB(1, m0 + 1, 1);
    if (it < 3){ GWRITE(0, 0); GISSUE(m0 + 2, 2); }
    SUB(1, m0 + 1, 2); SUB(1, m0 + 1, 3);
    if (it < 3){ GWRITE(0, 1); GISSUE(m0 + 2, 3); }
    SUB(1, m0 + 1, 4); SUB(1, m0 + 1, 5);
    if (it < 3){ GWRITE(0, 2); }
    SUB(1, m0 + 1, 6); SUB(1, m0 + 1, 7);
    if (it < 3){ GWRITE(0, 3); }
    __syncthreads();
  }

  // ---------------- epilogue 1: bias + leaky -> A1 bf16 (XOR-swizzled rows) ----
#pragma unroll
  for (int ct = 0; ct < 4; ++ct){
    const int col = (w << 6) + (ct << 4) + lr;
#pragma unroll
    for (int o = 0; o < 3; ++o)
#pragma unroll
      for (int tf = 0; tf < 2; ++tf)
#pragma unroll
        for (int r = 0; r < 4; ++r){
          float vv = acc[o][tf][ct][r] + b1c[ct];
          vv = vv > 0.f ? vv : 0.01f * vv;
          const int trow = (tf << 4) + (q << 2) + r;     // D row = 4*(lane>>4)+reg
          int byt = (((o << 5) + trow) << 10) + (col << 1);
          byt ^= (trow & 7) << 4;
          *(unsigned short*)(lds + byt) = f2bf(vv);
        }
  }
  __syncthreads();

  // ---------------- phase 2: out = mean_o leaky(A1 @ W2^T + b2), K=512, no barriers
  const char* bp2[4];
  float b2c[4];
#pragma unroll
  for (int ct = 0; ct < 4; ++ct){
    const int col = (w << 6) + (ct << 4) + lr;
    bp2[ct] = (const char*)w2b + col * 1024 + (q << 4);
    b2c[ct] = b2v[col];
  }
  f32x4 acc2[3][2][4];
#pragma unroll
  for (int o = 0; o < 3; ++o)
#pragma unroll
    for (int tf = 0; tf < 2; ++tf)
#pragma unroll
      for (int ct = 0; ct < 4; ++ct)
        acc2[o][tf][ct] = f32x4{0.f, 0.f, 0.f, 0.f};

  bf16x8 c0[4], c1[4];
#pragma unroll
  for (int ct = 0; ct < 4; ++ct) c0[ct] = *(const bf16x8*)(bp2[ct]);

#pragma unroll 1
  for (int it2 = 0; it2 < 8; ++it2){
    const int s0 = it2 << 1;
#pragma unroll
    for (int ct = 0; ct < 4; ++ct) c1[ct] = *(const bf16x8*)(bp2[ct] + ((s0 + 1) << 6));
    A2SUB(s0, c0);
    if (it2 < 7){
#pragma unroll
      for (int ct = 0; ct < 4; ++ct) c0[ct] = *(const bf16x8*)(bp2[ct] + ((s0 + 2) << 6));
    }
    A2SUB(s0 + 1, c1);
  }

  // ---------------- epilogue 2: bias + leaky + mean(o) -> [B,H,T] ----------------
#pragma unroll
  for (int tf = 0; tf < 2; ++tf)
#pragma unroll
    for (int ct = 0; ct < 4; ++ct){
      const int col = (w << 6) + (ct << 4) + lr;
      f32x4 ov;
#pragma unroll
      for (int r = 0; r < 4; ++r){
        float s = 0.f;
#pragma unroll
        for (int o = 0; o < 3; ++o){
          float vv = acc2[o][tf][ct][r] + b2c[ct];
          vv = vv > 0.f ? vv : 0.01f * vv;
          s += vv;
        }
        ov[r] = s * (1.f / 3.f);
      }
      *(f32x4*)(out + ((((long)b << 9) + col) << 8) + t0 + (tf << 4) + (q << 2)) = ov;
    }
}

extern "C" void kernel_launch(void* const* d_in, const int* in_sizes, int n_in,
                              void* d_out, int out_size, void* d_ws, size_t ws_size,
                              hipStream_t stream){
  const float* x  = (const float*)d_in[0];
  const float* w1 = (const float*)d_in[1];
  const float* b1 = (const float*)d_in[2];
  const float* w2 = (const float*)d_in[3];
  const float* b2 = (const float*)d_in[4];
  unsigned short* w1b = (unsigned short*)d_ws;            // 512*2048 bf16 = 2 MiB
  unsigned short* w2b = w1b + 512 * 2048;                 // 512*512  bf16 = 0.5 MiB
  conv_w_kernel<<<1280, 256, 0, stream>>>(w1, w2, w1b, w2b);
  fused_kernel<<<256, 512, 0, stream>>>(x, b1, b2, w1b, w2b, (float*)d_out);
}

// Round 4
// 90.976 us; speedup vs baseline: 2.7404x; 2.7404x over previous
//
#include <hip/hip_runtime.h>
#include <stdint.h>

typedef __attribute__((ext_vector_type(8))) __bf16 bf16x8;
typedef __attribute__((ext_vector_type(4))) float f32x4;

// Selected upper-tri circular-adjacency pairs (r,c), row-major triu order. K=64.
__device__ const unsigned char dR[64] = {
  0,0,0,0,0,0,0,
  1,1,1,1,1,1,
  2,2,2,2,2,
  3,3,3,3,
  4,4,4,4,
  5,5,5,5,
  6,6,6,6,
  7,7,7,7,
  8,8,8,8,
  9,9,9,9,
  10,10,10,10,
  11,11,11,11,
  12,12,12,12,
  13,13,13,
  14,14,
  15};
__device__ const unsigned char dC[64] = {
  0,1,2,3,13,14,15,
  1,2,3,4,14,15,
  2,3,4,5,15,
  3,4,5,6,
  4,5,6,7,
  5,6,7,8,
  6,7,8,9,
  7,8,9,10,
  8,9,10,11,
  9,10,11,12,
  10,11,12,13,
  11,12,13,14,
  12,13,14,15,
  13,14,15,
  14,15,
  15};

__device__ __forceinline__ unsigned short f2bf(float x){
  unsigned u = __builtin_bit_cast(unsigned, x);
  return (unsigned short)((u + 0x7FFFu + ((u >> 16) & 1u)) >> 16);
}

__device__ __forceinline__ void gl16(const void* g, void* l){
  __builtin_amdgcn_global_load_lds((const __attribute__((address_space(1))) unsigned int*)g,
                                   (__attribute__((address_space(3))) unsigned int*)l,
                                   16, 0, 0);
}

// fp32 -> bf16 weight conversion into workspace (2.62 MB total)
__global__ void conv_w_kernel(const float* __restrict__ w1, const float* __restrict__ w2,
                              unsigned short* __restrict__ o1, unsigned short* __restrict__ o2){
  int i = blockIdx.x * 256 + threadIdx.x;
  if (i < 262144){
    float4 v = ((const float4*)w1)[i];
    ushort4 pk; pk.x=f2bf(v.x); pk.y=f2bf(v.y); pk.z=f2bf(v.z); pk.w=f2bf(v.w);
    ((ushort4*)o1)[i] = pk;
  } else {
    int j = i - 262144;
    if (j < 65536){
      float4 v = ((const float4*)w2)[j];
      ushort4 pk; pk.x=f2bf(v.x); pk.y=f2bf(v.y); pk.z=f2bf(v.z); pk.w=f2bf(v.w);
      ((ushort4*)o2)[j] = pk;
    }
  }
}

// LDS: phase 1: wbuf dbuf 2x32KB @ 0/32768, abuf dbuf 2x6144 @ 65536/71680
//      phase 2: A1 [96 rows][512 h] bf16 XOR-swizzled @ 0..98304 (aliases, post-barrier)
#define LW0 0
#define LW1 32768
#define LA0 65536
#define LA1 71680

// One K=32 step: issue next W (gl_lds, dbuf) + next gather (regs), ds_read frags,
// 24 MFMA, cvt+ds_write next A tile, counted-drain + raw barrier.
#define STEP(CUR, NXT, FNXT, PARNXT, DO_PRE) do{                                          \
  float gv[3][2];                                                                         \
  if (DO_PRE){                                                                            \
    _Pragma("unroll") for (int i = 0; i < 4; ++i)                                         \
      gl16((const char*)w1b + wso[i] + ((2*(FNXT) + (PARNXT)) << 6),                      \
           lds + ((NXT) ? LW1 : LW0) + wdb[i]);                                           \
    _Pragma("unroll") for (int o = 0; o < 3; ++o)                                         \
      _Pragma("unroll") for (int e = 0; e < 2; ++e)                                       \
        gv[o][e] = xb[(long)(FNXT)*65536 + poff[PARNXT][o][e]];                           \
  }                                                                                       \
  bf16x8 af[6], bw[4];                                                                    \
  _Pragma("unroll") for (int fm = 0; fm < 6; ++fm)                                        \
    af[fm] = *(const bf16x8*)(lds + ((CUR) ? LA1 : LA0) + ard + fm*256);                  \
  _Pragma("unroll") for (int cn = 0; cn < 4; ++cn)                                        \
    bw[cn] = *(const bf16x8*)(lds + ((CUR) ? LW1 : LW0) + wrd[cn]);                       \
  __builtin_amdgcn_sched_barrier(0);                                                      \
  _Pragma("unroll") for (int cn = 0; cn < 4; ++cn)                                        \
    _Pragma("unroll") for (int fm = 0; fm < 6; ++fm)                                      \
      acc[fm][cn] = __builtin_amdgcn_mfma_f32_16x16x32_bf16(af[fm], bw[cn], acc[fm][cn], 0, 0, 0); \
  __builtin_amdgcn_sched_barrier(0);                                                      \
  if (DO_PRE){                                                                            \
    _Pragma("unroll") for (int o = 0; o < 3; ++o){                                        \
      unsigned pv = (unsigned)f2bf(gv[o][0]) | ((unsigned)f2bf(gv[o][1]) << 16);          \
      *(unsigned*)(lds + ((NXT) ? LA1 : LA0) + awr + (o << 9)) = pv;                      \
    }                                                                                     \
  }                                                                                       \
  asm volatile("s_waitcnt vmcnt(0) lgkmcnt(0)" ::: "memory");                             \
  __builtin_amdgcn_s_barrier();                                                           \
}while(0)

#define A2SUB(ss, cc) do{                                                                 \
  bf16x8 a2[6];                                                                           \
  _Pragma("unroll") for (int fm = 0; fm < 6; ++fm){                                       \
    int byt = (((fm << 4) + lr) << 10) + ((ss) << 6) + (q << 4);                          \
    byt ^= (lr & 7) << 4;                                                                 \
    a2[fm] = *(const bf16x8*)(lds + byt);                                                 \
  }                                                                                       \
  _Pragma("unroll") for (int cn = 0; cn < 4; ++cn)                                        \
    _Pragma("unroll") for (int fm = 0; fm < 6; ++fm)                                      \
      acc2[fm][cn] = __builtin_amdgcn_mfma_f32_16x16x32_bf16(a2[fm], cc[cn], acc2[fm][cn], 0, 0, 0); \
}while(0)

// Block = (b, 32-t tile): 256 blocks, 512 threads (8 waves). Each wave: [96m x 64n].
__global__ __launch_bounds__(512, 2)
void fused_kernel(const float* __restrict__ x,
                  const float* __restrict__ b1v,
                  const float* __restrict__ b2v,
                  const unsigned short* __restrict__ w1b,
                  const unsigned short* __restrict__ w2b,
                  float* __restrict__ out)
{
  __shared__ char lds[98304];
  const int bid = blockIdx.x;
  const int b   = bid >> 3;
  const int t0  = (bid & 7) << 5;

  const int tid  = threadIdx.x;
  const int w    = tid >> 6;
  const int lane = tid & 63;
  const int q    = lane >> 4;
  const int lr   = lane & 15;
  const int u    = tid >> 5;          // [0,16): k-pair index for gather
  const int tt   = tid & 31;          // t within tile for gather

  // gather source offsets: k = par*32 + 2u + e
  int poff[2][3][2];
#pragma unroll
  for (int par = 0; par < 2; ++par)
#pragma unroll
    for (int e = 0; e < 2; ++e){
      const int k = par * 32 + 2 * u + e;
      const int r = dR[k], c = dC[k];
#pragma unroll
      for (int o = 0; o < 3; ++o){
        const int v = o - 1;                         // mean over o is order-free
        poff[par][o][e] = ((((r - v) & 15) << 4) | ((c - v) & 15)) << 8;
      }
    }
  const float* xb = x + (((long)b << 21) + t0 + tt);

  // A-tile ds_write base: layout [kb4][row96][16B], kb stride 1536
  const int awr = ((u >> 2) * 1536) + (tt << 4) + ((u & 3) << 2);   // + o*512
  // A-frag read base (conflict-free: 16 consecutive rows per lane-quarter)
  const int ard = q * 1536 + (lr << 4);                              // + fm*256
  // W-frag read offsets ([col][k] pitch 64B, slot-swizzled: free)
  int wrd[4];
#pragma unroll
  for (int cn = 0; cn < 4; ++cn){
    const int col = (w << 6) + (cn << 4) + lr;
    wrd[cn] = col * 64 + ((q ^ ((col >> 1) & 3)) << 4);
  }
  // W stage: linear LDS dest (wave-uniform base), inverse-swizzled global source
  int wso[4], wdb[4];
#pragma unroll
  for (int i = 0; i < 4; ++i){
    const int colb = (w << 6) + (i << 4);
    const int col  = colb + (lane >> 2);
    wso[i] = col * 4096 + (((lane & 3) ^ ((col >> 1) & 3)) << 4);
    wdb[i] = colb * 64;
  }

  f32x4 acc[6][4];
#pragma unroll
  for (int fm = 0; fm < 6; ++fm)
#pragma unroll
    for (int cn = 0; cn < 4; ++cn)
      acc[fm][cn] = f32x4{0.f, 0.f, 0.f, 0.f};

  // ---------------- prologue: stage step 0 (f=0, par=0) ----------------
  {
#pragma unroll
    for (int i = 0; i < 4; ++i)
      gl16((const char*)w1b + wso[i], lds + LW0 + wdb[i]);
    float gv[3][2];
#pragma unroll
    for (int o = 0; o < 3; ++o)
#pragma unroll
      for (int e = 0; e < 2; ++e)
        gv[o][e] = xb[poff[0][o][e]];
#pragma unroll
    for (int o = 0; o < 3; ++o){
      unsigned pv = (unsigned)f2bf(gv[o][0]) | ((unsigned)f2bf(gv[o][1]) << 16);
      *(unsigned*)(lds + LA0 + awr + (o << 9)) = pv;
    }
    asm volatile("s_waitcnt vmcnt(0) lgkmcnt(0)" ::: "memory");
    __builtin_amdgcn_s_barrier();
  }

  // ---------------- phase 1: 64 K-steps, one raw barrier each ----------------
#pragma unroll 1
  for (int it = 0; it < 31; ++it){
    STEP(0, 1, it,     1, 1);      // even step 2it,   prefetch 2it+1
    STEP(1, 0, it + 1, 0, 1);      // odd step 2it+1,  prefetch 2it+2
  }
  STEP(0, 1, 31, 1, 1);            // step 62, prefetch 63
  STEP(1, 0, 0, 0, 0);             // step 63, no prefetch

  // ---------------- epilogue 1: bias + leaky -> A1 bf16 (XOR-swizzled) --------
#pragma unroll
  for (int cn = 0; cn < 4; ++cn){
    const int h  = (w << 6) + (cn << 4) + lr;
    const float bb = b1v[h];
#pragma unroll
    for (int fm = 0; fm < 6; ++fm)
#pragma unroll
      for (int r = 0; r < 4; ++r){
        float vv = acc[fm][cn][r] + bb;
        vv = vv > 0.f ? vv : 0.01f * vv;
        const int row = (fm << 4) + (q << 2) + r;    // D row = 4*(lane>>4)+reg
        int byt = (row << 10) + (h << 1);
        byt ^= (row & 7) << 4;
        *(unsigned short*)(lds + byt) = f2bf(vv);
      }
  }
  asm volatile("s_waitcnt lgkmcnt(0)" ::: "memory");
  __builtin_amdgcn_s_barrier();

  // ---------------- phase 2: K=512 vs W2 (direct L2 frags), barrier-free ------
  int w2off[4];
#pragma unroll
  for (int cn = 0; cn < 4; ++cn){
    const int col = (w << 6) + (cn << 4) + lr;
    w2off[cn] = col * 1024 + (q << 4);
  }
  const char* w2c = (const char*)w2b;
  f32x4 acc2[6][4];
#pragma unroll
  for (int fm = 0; fm < 6; ++fm)
#pragma unroll
    for (int cn = 0; cn < 4; ++cn)
      acc2[fm][cn] = f32x4{0.f, 0.f, 0.f, 0.f};

  bf16x8 c0[4], c1[4];
#pragma unroll
  for (int cn = 0; cn < 4; ++cn) c0[cn] = *(const bf16x8*)(w2c + w2off[cn]);

#pragma unroll 1
  for (int it2 = 0; it2 < 8; ++it2){
    const int s0 = it2 << 1;
#pragma unroll
    for (int cn = 0; cn < 4; ++cn) c1[cn] = *(const bf16x8*)(w2c + w2off[cn] + ((s0 + 1) << 6));
    A2SUB(s0, c0);
    if (it2 < 7){
#pragma unroll
      for (int cn = 0; cn < 4; ++cn) c0[cn] = *(const bf16x8*)(w2c + w2off[cn] + ((s0 + 2) << 6));
    }
    A2SUB(s0 + 1, c1);
  }

  // ---------------- epilogue 2: bias + leaky + mean(o) -> [B,H,T] -------------
#pragma unroll
  for (int cn = 0; cn < 4; ++cn){
    const int h  = (w << 6) + (cn << 4) + lr;
    const float bb = b2v[h];
#pragma unroll
    for (int p = 0; p < 2; ++p){
      f32x4 ov;
#pragma unroll
      for (int r = 0; r < 4; ++r){
        float s = 0.f;
#pragma unroll
        for (int oo = 0; oo < 3; ++oo){
          float vv = acc2[oo * 2 + p][cn][r] + bb;
          vv = vv > 0.f ? vv : 0.01f * vv;
          s += vv;
        }
        ov[r] = s * (1.f / 3.f);
      }
      *(f32x4*)(out + (((long)b * 512 + h) << 8) + t0 + (p << 4) + (q << 2)) = ov;
    }
  }
}

extern "C" void kernel_launch(void* const* d_in, const int* in_sizes, int n_in,
                              void* d_out, int out_size, void* d_ws, size_t ws_size,
                              hipStream_t stream){
  const float* x  = (const float*)d_in[0];
  const float* w1 = (const float*)d_in[1];
  const float* b1 = (const float*)d_in[2];
  const float* w2 = (const float*)d_in[3];
  const float* b2 = (const float*)d_in[4];
  unsigned short* w1b = (unsigned short*)d_ws;            // 512*2048 bf16 = 2 MiB
  unsigned short* w2b = w1b + 512 * 2048;                 // 512*512  bf16 = 0.5 MiB
  conv_w_kernel<<<1280, 256, 0, stream>>>(w1, w2, w1b, w2b);
  fused_kernel<<<256, 512, 0, stream>>>(x, b1, b2, w1b, w2b, (float*)d_out);
}